// Round 8
// baseline (289.763 us; speedup 1.0000x reference)
//
#include <hip/hip_runtime.h>
#include <hip/hip_cooperative_groups.h>

namespace cg = cooperative_groups;

#define HIDDEN 128

typedef float v4f __attribute__((ext_vector_type(4)));

__device__ __forceinline__ float dot4(const v4f a, const v4f b) {
    return a.x * b.x + a.y * b.y + a.z * b.z + a.w * b.w;
}

// Single cooperative kernel.
// Phase A: nsd[n] = {dot(node[n],W_s), dot(node[n],W_d)}   (grid-stride)
// Phase B: out[e] = dot(edge_hidden[e], W_e)               (grid-stride)
//   A and B have no barrier between them: blocks drain A at different times,
//   so the node and edge streams overlap and HBM stays saturated.
// grid.sync()
// Phase C: out[e] += nsd[src].x + nsd[dst].y + b           (one edge/lane)
__global__ __launch_bounds__(256, 4)
void fused_decoder_kernel(const float* __restrict__ node_hidden,
                          const float* __restrict__ edge_hidden,
                          const int*   __restrict__ edge_index, // [2][n_edges]
                          const float* __restrict__ W,          // [384]
                          const float* __restrict__ b,          // [1]
                          float2* __restrict__ nsd,             // [n_nodes]
                          float* __restrict__ out,              // [n_edges]
                          int n_nodes, int n_edges) {
    const int lane     = threadIdx.x & 31;
    const int tid      = blockIdx.x * blockDim.x + threadIdx.x;
    const int nthreads = gridDim.x * blockDim.x;
    const int ngroups  = nthreads >> 5;
    const int grp      = tid >> 5;

    const v4f we = reinterpret_cast<const v4f*>(W)[lane];
    const v4f ws = reinterpret_cast<const v4f*>(W + HIDDEN)[lane];
    const v4f wd = reinterpret_cast<const v4f*>(W + 2 * HIDDEN)[lane];

    // ---- Phase A: node dots ----
    for (int n = grp; n < n_nodes; n += ngroups) {
        const v4f v = reinterpret_cast<const v4f*>(node_hidden + (size_t)n * HIDDEN)[lane];
        float as = dot4(v, ws);
        float ad = dot4(v, wd);
        #pragma unroll
        for (int off = 16; off > 0; off >>= 1) {
            as += __shfl_down(as, off, 32);
            ad += __shfl_down(ad, off, 32);
        }
        if (lane == 0)
            nsd[n] = make_float2(as, ad);
    }

    // ---- Phase B: edge dots, 4 edges per 32-lane group ----
    const int n_g4 = (n_edges + 3) >> 2;
    for (int g = grp; g < n_g4; g += ngroups) {
        const int e0 = g * 4;
        if (e0 + 4 <= n_edges) {
            const v4f* r = reinterpret_cast<const v4f*>(edge_hidden) + (size_t)e0 * 32 + lane;
            const v4f x0 = r[0];
            const v4f x1 = r[32];
            const v4f x2 = r[64];
            const v4f x3 = r[96];

            float a0 = dot4(x0, we);
            float a1 = dot4(x1, we);
            float a2 = dot4(x2, we);
            float a3 = dot4(x3, we);

            #pragma unroll
            for (int off = 16; off > 0; off >>= 1) {
                a0 += __shfl_xor(a0, off, 32);
                a1 += __shfl_xor(a1, off, 32);
                a2 += __shfl_xor(a2, off, 32);
                a3 += __shfl_xor(a3, off, 32);
            }
            if (lane < 4)
                out[e0 + lane] = (lane == 0) ? a0 : (lane == 1) ? a1 : (lane == 2) ? a2 : a3;
        } else {
            for (int e = e0; e < n_edges; ++e) {
                const v4f x = reinterpret_cast<const v4f*>(edge_hidden + (size_t)e * HIDDEN)[lane];
                float a = dot4(x, we);
                #pragma unroll
                for (int off = 16; off > 0; off >>= 1)
                    a += __shfl_down(a, off, 32);
                if (lane == 0) out[e] = a;
            }
        }
    }

    __threadfence();
    cg::this_grid().sync();

    // ---- Phase C: gather base and accumulate ----
    const float bias = b[0];
    for (int e = tid; e < n_edges; e += nthreads) {
        const int s = edge_index[e];
        const int d = edge_index[n_edges + e];
        out[e] += nsd[s].x + nsd[d].y + bias;
    }
}

// ---------- fallback path (R6 structure) ----------
__global__ __launch_bounds__(256)
void node_dots_kernel(const float* __restrict__ node_hidden,
                      const float* __restrict__ W,
                      float2* __restrict__ nsd,
                      int n_nodes) {
    const int tid  = blockIdx.x * blockDim.x + threadIdx.x;
    const int node = tid >> 5;
    const int lane = tid & 31;
    if (node >= n_nodes) return;

    const v4f v  = reinterpret_cast<const v4f*>(node_hidden + (size_t)node * HIDDEN)[lane];
    const v4f ws = reinterpret_cast<const v4f*>(W + HIDDEN)[lane];
    const v4f wd = reinterpret_cast<const v4f*>(W + 2 * HIDDEN)[lane];

    float as = dot4(v, ws);
    float ad = dot4(v, wd);
    #pragma unroll
    for (int off = 16; off > 0; off >>= 1) {
        as += __shfl_down(as, off, 32);
        ad += __shfl_down(ad, off, 32);
    }
    if (lane == 0)
        nsd[node] = make_float2(as, ad);
}

__global__ __launch_bounds__(256)
void edge_fused_kernel(const float* __restrict__ edge_hidden,
                       const int*   __restrict__ edge_index,
                       const float* __restrict__ W,
                       const float* __restrict__ b,
                       const float2* __restrict__ nsd,
                       float* __restrict__ out,
                       int n_edges) {
    const int tid  = blockIdx.x * blockDim.x + threadIdx.x;
    const int grp  = tid >> 5;
    const int lane = tid & 31;
    const int e0   = grp * 4;
    if (e0 >= n_edges) return;

    float base = 0.0f;
    const int my_e = e0 + lane;
    if (lane < 4 && my_e < n_edges) {
        const int s = edge_index[my_e];
        const int d = edge_index[n_edges + my_e];
        base = nsd[s].x + nsd[d].y + b[0];
    }

    const v4f we = reinterpret_cast<const v4f*>(W)[lane];
    const v4f* r = reinterpret_cast<const v4f*>(edge_hidden) + (size_t)e0 * 32 + lane;
    const v4f x0 = r[0];
    const v4f x1 = r[32];
    const v4f x2 = r[64];
    const v4f x3 = r[96];

    float a0 = dot4(x0, we);
    float a1 = dot4(x1, we);
    float a2 = dot4(x2, we);
    float a3 = dot4(x3, we);

    #pragma unroll
    for (int off = 16; off > 0; off >>= 1) {
        a0 += __shfl_xor(a0, off, 32);
        a1 += __shfl_xor(a1, off, 32);
        a2 += __shfl_xor(a2, off, 32);
        a3 += __shfl_xor(a3, off, 32);
    }

    if (lane < 4 && my_e < n_edges) {
        const float a = (lane == 0) ? a0 : (lane == 1) ? a1 : (lane == 2) ? a2 : a3;
        out[my_e] = a + base;
    }
}

extern "C" void kernel_launch(void* const* d_in, const int* in_sizes, int n_in,
                              void* d_out, int out_size, void* d_ws, size_t ws_size,
                              hipStream_t stream) {
    const float* node_hidden = (const float*)d_in[0];
    const float* edge_hidden = (const float*)d_in[1];
    const int*   edge_index  = (const int*)d_in[2];
    const float* W           = (const float*)d_in[3];
    const float* b           = (const float*)d_in[4];
    float* out = (float*)d_out;

    int n_nodes = in_sizes[0] / HIDDEN;
    int n_edges = in_sizes[2] / 2;

    float2* nsd = (float2*)d_ws;   // 800 KB

    // Cooperative single-dispatch path. 1024 blocks x 256 thr co-resident
    // (launch_bounds(256,4) -> >=4 blocks/CU x 256 CUs).
    void* args[] = {(void*)&node_hidden, (void*)&edge_hidden, (void*)&edge_index,
                    (void*)&W, (void*)&b, (void*)&nsd, (void*)&out,
                    (void*)&n_nodes, (void*)&n_edges};
    hipError_t err = hipLaunchCooperativeKernel((const void*)fused_decoder_kernel,
                                                dim3(1024), dim3(256), args, 0, stream);
    if (err == hipSuccess) return;

    // Fallback: R6 two-kernel structure.
    {
        const int threads = 256;
        const int blocks = (n_nodes * 32 + threads - 1) / threads;
        node_dots_kernel<<<blocks, threads, 0, stream>>>(node_hidden, W, nsd, n_nodes);
    }
    {
        const int threads = 256;
        const int groups  = (n_edges + 3) / 4;
        const int blocks  = (groups * 32 + threads - 1) / threads;
        edge_fused_kernel<<<blocks, threads, 0, stream>>>(edge_hidden, edge_index, W, b,
                                                          nsd, out, n_edges);
    }
}

// Round 9
// 65.053 us; speedup vs baseline: 4.4543x; 4.4543x over previous
//
#include <hip/hip_runtime.h>

#define HIDDEN 128

typedef float v4f __attribute__((ext_vector_type(4)));

__device__ __forceinline__ float dot4(const v4f a, const v4f b) {
    return a.x * b.x + a.y * b.y + a.z * b.z + a.w * b.w;
}

// Phase 1: nsd[n] = {dot(node[n],W_s), dot(node[n],W_d)}.
// 4 nodes per 32-lane group: 4 independent 512B row loads in flight,
// 8 interleaved butterfly-reduce chains. Streams use nontemporal loads
// (single-use data; keep L2 for the nsd table).
__global__ __launch_bounds__(256)
void node_dots_kernel(const float* __restrict__ node_hidden,
                      const float* __restrict__ W,     // [384]
                      float2* __restrict__ nsd,        // [n_nodes]
                      int n_nodes) {
    const int tid  = blockIdx.x * blockDim.x + threadIdx.x;
    const int grp  = tid >> 5;
    const int lane = tid & 31;
    const int n0   = grp * 4;
    if (n0 >= n_nodes) return;

    const v4f ws = reinterpret_cast<const v4f*>(W + HIDDEN)[lane];
    const v4f wd = reinterpret_cast<const v4f*>(W + 2 * HIDDEN)[lane];

    if (n0 + 4 <= n_nodes) {
        const v4f* r = reinterpret_cast<const v4f*>(node_hidden) + (size_t)n0 * 32 + lane;
        const v4f x0 = __builtin_nontemporal_load(r + 0);
        const v4f x1 = __builtin_nontemporal_load(r + 32);
        const v4f x2 = __builtin_nontemporal_load(r + 64);
        const v4f x3 = __builtin_nontemporal_load(r + 96);

        float as0 = dot4(x0, ws), ad0 = dot4(x0, wd);
        float as1 = dot4(x1, ws), ad1 = dot4(x1, wd);
        float as2 = dot4(x2, ws), ad2 = dot4(x2, wd);
        float as3 = dot4(x3, ws), ad3 = dot4(x3, wd);

        #pragma unroll
        for (int off = 16; off > 0; off >>= 1) {
            as0 += __shfl_xor(as0, off, 32);
            ad0 += __shfl_xor(ad0, off, 32);
            as1 += __shfl_xor(as1, off, 32);
            ad1 += __shfl_xor(ad1, off, 32);
            as2 += __shfl_xor(as2, off, 32);
            ad2 += __shfl_xor(ad2, off, 32);
            as3 += __shfl_xor(as3, off, 32);
            ad3 += __shfl_xor(ad3, off, 32);
        }

        if (lane < 4) {
            const float as = (lane == 0) ? as0 : (lane == 1) ? as1 : (lane == 2) ? as2 : as3;
            const float ad = (lane == 0) ? ad0 : (lane == 1) ? ad1 : (lane == 2) ? ad2 : ad3;
            nsd[n0 + lane] = make_float2(as, ad);
        }
    } else {
        for (int n = n0; n < n_nodes; ++n) {
            const v4f v = reinterpret_cast<const v4f*>(node_hidden + (size_t)n * HIDDEN)[lane];
            float as = dot4(v, ws);
            float ad = dot4(v, wd);
            #pragma unroll
            for (int off = 16; off > 0; off >>= 1) {
                as += __shfl_down(as, off, 32);
                ad += __shfl_down(ad, off, 32);
            }
            if (lane == 0) nsd[n] = make_float2(as, ad);
        }
    }
}

// Phase 2 (fused): out[e] = dot(edge_hidden[e], W_e) + nsd[src].x + nsd[dst].y + b.
// 8 edges per 32-lane group. Lanes 0-7 each own one edge's gather chain
// (issued FIRST so the ~L2 gather latency hides under the 8-row stream +
// reduce). Butterfly reduce -> all lanes hold all 8 sums; lanes 0-7 write
// 32 contiguous bytes.
__global__ __launch_bounds__(256)
void edge_fused_kernel(const float* __restrict__ edge_hidden,
                       const int*   __restrict__ edge_index, // [2][n_edges]
                       const float* __restrict__ W,          // [384]
                       const float* __restrict__ b,          // [1]
                       const float2* __restrict__ nsd,
                       float* __restrict__ out,
                       int n_edges) {
    const int tid  = blockIdx.x * blockDim.x + threadIdx.x;
    const int grp  = tid >> 5;
    const int lane = tid & 31;
    const int e0   = grp * 8;
    if (e0 >= n_edges) return;

    // epilogue gather first (lanes 0-7) — overlapped with the stream below
    float base = 0.0f;
    const int my_e = e0 + lane;
    if (lane < 8 && my_e < n_edges) {
        const int s = edge_index[my_e];
        const int d = edge_index[n_edges + my_e];
        base = nsd[s].x + nsd[d].y + b[0];
    }

    const v4f we = reinterpret_cast<const v4f*>(W)[lane];

    if (e0 + 8 <= n_edges) {
        const v4f* r = reinterpret_cast<const v4f*>(edge_hidden) + (size_t)e0 * 32 + lane;
        const v4f x0 = __builtin_nontemporal_load(r + 0);
        const v4f x1 = __builtin_nontemporal_load(r + 32);
        const v4f x2 = __builtin_nontemporal_load(r + 64);
        const v4f x3 = __builtin_nontemporal_load(r + 96);
        const v4f x4 = __builtin_nontemporal_load(r + 128);
        const v4f x5 = __builtin_nontemporal_load(r + 160);
        const v4f x6 = __builtin_nontemporal_load(r + 192);
        const v4f x7 = __builtin_nontemporal_load(r + 224);

        float a0 = dot4(x0, we);
        float a1 = dot4(x1, we);
        float a2 = dot4(x2, we);
        float a3 = dot4(x3, we);
        float a4 = dot4(x4, we);
        float a5 = dot4(x5, we);
        float a6 = dot4(x6, we);
        float a7 = dot4(x7, we);

        #pragma unroll
        for (int off = 16; off > 0; off >>= 1) {
            a0 += __shfl_xor(a0, off, 32);
            a1 += __shfl_xor(a1, off, 32);
            a2 += __shfl_xor(a2, off, 32);
            a3 += __shfl_xor(a3, off, 32);
            a4 += __shfl_xor(a4, off, 32);
            a5 += __shfl_xor(a5, off, 32);
            a6 += __shfl_xor(a6, off, 32);
            a7 += __shfl_xor(a7, off, 32);
        }

        if (lane < 8) {
            const float a = (lane == 0) ? a0 : (lane == 1) ? a1 : (lane == 2) ? a2 :
                            (lane == 3) ? a3 : (lane == 4) ? a4 : (lane == 5) ? a5 :
                            (lane == 6) ? a6 : a7;
            out[my_e] = a + base;
        }
    } else {
        for (int e = e0; e < n_edges; ++e) {
            const v4f x = reinterpret_cast<const v4f*>(edge_hidden + (size_t)e * HIDDEN)[lane];
            float a = dot4(x, we);
            #pragma unroll
            for (int off = 16; off > 0; off >>= 1)
                a += __shfl_down(a, off, 32);
            if (lane == 0) {
                const int s = edge_index[e];
                const int d = edge_index[n_edges + e];
                out[e] = a + nsd[s].x + nsd[d].y + b[0];
            }
        }
    }
}

extern "C" void kernel_launch(void* const* d_in, const int* in_sizes, int n_in,
                              void* d_out, int out_size, void* d_ws, size_t ws_size,
                              hipStream_t stream) {
    const float* node_hidden = (const float*)d_in[0];
    const float* edge_hidden = (const float*)d_in[1];
    const int*   edge_index  = (const int*)d_in[2];
    const float* W           = (const float*)d_in[3];
    const float* b           = (const float*)d_in[4];
    float* out = (float*)d_out;

    const int n_nodes = in_sizes[0] / HIDDEN;
    const int n_edges = in_sizes[2] / 2;

    float2* nsd = (float2*)d_ws;   // 800 KB

    {
        const int threads = 256;
        const int groups  = (n_nodes + 3) / 4;                 // 4 nodes / 32-lane group
        const int blocks  = (groups * 32 + threads - 1) / threads;
        node_dots_kernel<<<blocks, threads, 0, stream>>>(node_hidden, W, nsd, n_nodes);
    }
    {
        const int threads = 256;
        const int groups  = (n_edges + 7) / 8;                 // 8 edges / 32-lane group
        const int blocks  = (groups * 32 + threads - 1) / threads;
        edge_fused_kernel<<<blocks, threads, 0, stream>>>(edge_hidden, edge_index, W, b,
                                                          nsd, out, n_edges);
    }
}